// Round 11
// baseline (390.770 us; speedup 1.0000x reference)
//
#include <hip/hip_runtime.h>
#include <hip/hip_bf16.h>

#define NN 50000
#define NE 800000
#define NPAIR 100000

typedef unsigned int u32;
typedef unsigned short u16;
typedef __attribute__((ext_vector_type(8))) short short8;
typedef __attribute__((ext_vector_type(4))) float f32x4;

__device__ __forceinline__ float bflo(u32 u) { return __uint_as_float(u << 16); }
__device__ __forceinline__ float bfhi(u32 u) { return __uint_as_float(u & 0xffff0000u); }
__device__ __forceinline__ u32 bfround(float f) {
    u32 u = __float_as_uint(f);
    return (u + 0x7fffu + ((u >> 16) & 1u)) >> 16;
}
__device__ __forceinline__ u32 packbf(float a, float b) {
    return bfround(a) | (bfround(b) << 16);
}

// ---------------- CSR build ----------------
__global__ __launch_bounds__(256) void count_kernel(const int* __restrict__ dst, int* __restrict__ off) {
    int e = blockIdx.x * 256 + threadIdx.x;
    if (e < NE) atomicAdd(&off[dst[e] + 1], 1);
}

__global__ __launch_bounds__(256) void scan1(int* __restrict__ data, int* __restrict__ bsums, int n) {
    int tid = threadIdx.x;
    int i = blockIdx.x * 256 + tid;
    int v = (i < n) ? data[i] : 0;
    #pragma unroll
    for (int d = 1; d < 64; d <<= 1) {
        int t = __shfl_up(v, d);
        if ((tid & 63) >= d) v += t;
    }
    __shared__ int ws[4];
    if ((tid & 63) == 63) ws[tid >> 6] = v;
    __syncthreads();
    int w = tid >> 6;
    if (w > 0) v += ws[0];
    if (w > 1) v += ws[1];
    if (w > 2) v += ws[2];
    if (i < n) data[i] = v;
    if (tid == 255) bsums[blockIdx.x] = v;
}

__global__ __launch_bounds__(256) void scan2(int* __restrict__ bsums, int nb) {
    int tid = threadIdx.x;
    int v = (tid < nb) ? bsums[tid] : 0;
    #pragma unroll
    for (int d = 1; d < 64; d <<= 1) {
        int t = __shfl_up(v, d);
        if ((tid & 63) >= d) v += t;
    }
    __shared__ int ws[4];
    if ((tid & 63) == 63) ws[tid >> 6] = v;
    __syncthreads();
    int w = tid >> 6;
    if (w > 0) v += ws[0];
    if (w > 1) v += ws[1];
    if (w > 2) v += ws[2];
    if (tid < nb) bsums[tid] = v;
}

__global__ __launch_bounds__(256) void scan3(int* __restrict__ data, const int* __restrict__ bsums, int n) {
    int i = blockIdx.x * 256 + threadIdx.x;
    if (i < n && blockIdx.x > 0) data[i] += bsums[blockIdx.x - 1];
}

// stores SRC NODE VALUE (not edge id) -> aggregate skips one indirection
__global__ __launch_bounds__(256) void fill_kernel(const int* __restrict__ src, const int* __restrict__ dst,
                                                   const int* __restrict__ off,
                                                   int* __restrict__ cursor, int* __restrict__ srcs) {
    int e = blockIdx.x * 256 + threadIdx.x;
    if (e < NE) {
        int d = dst[e];
        int pos = off[d] + atomicAdd(&cursor[d], 1);
        srcs[pos] = src[e];
    }
}

// ---- merged weight packing: W0,W1 -> GEMM B-frag order; w1 -> MLP B-frag order ----
__global__ __launch_bounds__(256) void pack_all(const float* __restrict__ W0, const float* __restrict__ W1,
                                                const float* __restrict__ w1,
                                                u16* __restrict__ w0pg, u16* __restrict__ w1pg,
                                                u16* __restrict__ w1p) {
    int id = blockIdx.x * 256 + threadIdx.x;
    if (id < 65536) {
        const float* W = (id < 32768) ? W0 : W1;
        u16* Wp = (id < 32768) ? w0pg : w1pg;
        int t = id & 32767;
        int k = t >> 8, n = t & 255;
        int kt = k >> 5, kk = k & 31, lg = kk >> 3, j = kk & 7;
        int nt = n >> 4, ln = n & 15;
        int lane = lg * 16 + ln;
        Wp[(((kt * 16 + nt) * 64) + lane) * 8 + j] = (u16)bfround(W[t]);
    } else if (id < 65536 + 49152) {
        int t = id - 65536;
        int k = t >> 7, n = t & 127;
        int kt = k >> 5, kk = k & 31, lg = kk >> 3, j = kk & 7;
        int ct = n >> 4, ln = n & 15;
        int lane = lg * 16 + ln;
        w1p[(((kt * 8 + ct) * 64) + lane) * 8 + j] = (u16)bfround(w1[t]);
    }
}

// ---- MFMA GEMM + attention-coef: C(bf16)[nrows,256] = A[nrows,128]@W ; el/er ----
template<bool ABF16>
__global__ __launch_bounds__(256) void gemm_mfma(const void* __restrict__ Av,
                                                 const u16* __restrict__ Wp,
                                                 const float* __restrict__ al,
                                                 const float* __restrict__ ar,
                                                 u16* __restrict__ C,
                                                 float* __restrict__ att, int nrows) {
    __shared__ u16 sbuf[64 * 264];
    int rbase = blockIdx.x * 64;
    int tid = threadIdx.x;
    if (ABF16) {
        const uint4* A4 = (const uint4*)Av;
        for (int id = tid; id < 64 * 16; id += 256) {
            int r = id >> 4, seg = id & 15;
            int gr = rbase + r;
            uint4 v = make_uint4(0u, 0u, 0u, 0u);
            if (gr < nrows) v = A4[gr * 16 + seg];
            *(uint4*)&sbuf[r * 136 + seg * 8] = v;
        }
    } else {
        const float4* A4 = (const float4*)Av;
        for (int id = tid; id < 64 * 32; id += 256) {
            int r = id >> 5, seg = id & 31;
            int gr = rbase + r;
            float4 v = make_float4(0.f, 0.f, 0.f, 0.f);
            if (gr < nrows) v = A4[gr * 32 + seg];
            uint2 p;
            p.x = packbf(v.x, v.y);
            p.y = packbf(v.z, v.w);
            *(uint2*)&sbuf[r * 136 + seg * 4] = p;
        }
    }
    __syncthreads();
    int l = tid & 63, w = tid >> 6;
    int ln = l & 15, lg = l >> 4;
    f32x4 acc[16];
    #pragma unroll
    for (int nt = 0; nt < 16; ++nt) acc[nt] = (f32x4){0.f, 0.f, 0.f, 0.f};
    const short8* wp = (const short8*)Wp;
    const u16* arow = &sbuf[(w * 16 + ln) * 136 + lg * 8];
    #pragma unroll
    for (int kt = 0; kt < 4; ++kt) {
        short8 a = *(const short8*)&arow[kt * 32];
        #pragma unroll
        for (int nt = 0; nt < 16; ++nt) {
            short8 b = wp[(kt * 16 + nt) * 64 + l];
            acc[nt] = __builtin_amdgcn_mfma_f32_16x16x32_bf16(a, b, acc[nt], 0, 0, 0);
        }
    }
    float alv[16], arv[16];
    #pragma unroll
    for (int nt = 0; nt < 16; ++nt) {
        alv[nt] = al[nt * 16 + ln];
        arv[nt] = ar[nt * 16 + ln];
    }
    #pragma unroll
    for (int r = 0; r < 4; ++r) {
        float pl0 = 0.f, pr0 = 0.f, pl1 = 0.f, pr1 = 0.f;
        #pragma unroll
        for (int nt = 0; nt < 8; ++nt) {
            pl0 += acc[nt][r] * alv[nt];
            pr0 += acc[nt][r] * arv[nt];
            pl1 += acc[nt + 8][r] * alv[nt + 8];
            pr1 += acc[nt + 8][r] * arv[nt + 8];
        }
        #pragma unroll
        for (int m = 1; m < 16; m <<= 1) {
            pl0 += __shfl_xor(pl0, m); pr0 += __shfl_xor(pr0, m);
            pl1 += __shfl_xor(pl1, m); pr1 += __shfl_xor(pr1, m);
        }
        int grow = rbase + w * 16 + lg * 4 + r;
        if (ln == 0 && grow < nrows) {
            att[grow * 4 + 0] = pl0;
            att[grow * 4 + 1] = pl1;
            att[grow * 4 + 2] = pr0;
            att[grow * 4 + 3] = pr1;
        }
    }
    __syncthreads();
    #pragma unroll
    for (int nt = 0; nt < 16; ++nt) {
        int col = nt * 16 + ln;
        #pragma unroll
        for (int r = 0; r < 4; ++r) {
            int row = w * 16 + lg * 4 + r;
            sbuf[row * 264 + col] = (u16)bfround(acc[nt][r]);
        }
    }
    __syncthreads();
    uint4* C4 = (uint4*)C;
    for (int id = tid; id < 64 * 32; id += 256) {
        int r = id >> 5, seg = id & 31;
        int gr = rbase + r;
        if (gr < nrows) C4[gr * 32 + seg] = *(uint4*)&sbuf[r * 264 + seg * 8];
    }
}

// ------- aggregate: 1 wave/node; 2 edges per wave-load (uint4/lane, 1 KB/instr) -------
// ALL __shfl are executed unconditionally (convergent ops must not sit under a
// lane-divergent ternary/branch: bpermute from exec-masked-off source lanes is
// undefined -> the R10 correctness bug). Selection happens afterwards in registers.
__global__ __launch_bounds__(256) void aggregate(const u16* __restrict__ feat,
                                                 const int* __restrict__ off,
                                                 const int* __restrict__ srcs,
                                                 const float* __restrict__ att,
                                                 u16* __restrict__ hout) {
    int v = blockIdx.x * 4 + (threadIdx.x >> 6);
    int lane = threadIdx.x & 63;
    if (v >= NN) return;
    int s = off[v], deg = off[v + 1] - s;
    const float4* att4 = (const float4*)att;
    const uint4* feat4 = (const uint4*)feat;
    uint4* hout4 = (uint4*)hout;
    int seg = lane & 31;
    int halfsel = lane >> 5;           // edge parity within pair
    int headbit = (lane >> 4) & 1;     // head of this lane's columns
    if (deg == 0) {
        if (lane < 16) hout4[(size_t)v * 16 + lane] = make_uint4(0u, 0u, 0u, 0u);
        return;
    }
    float4 av = att4[v];
    float er0 = av.z, er1 = av.w;
    float m0 = -1e30f, m1 = -1e30f, d0 = 0.f, d1 = 0.f;
    float a0 = 0.f, a1 = 0.f, a2 = 0.f, a3 = 0.f, a4 = 0.f, a5 = 0.f, a6 = 0.f, a7 = 0.f;

    for (int cb = 0; cb < deg; cb += 64) {
        int k = cb + lane;
        int cn = min(64, deg - cb);
        int u = 0;
        float e0 = -1e30f, e1 = -1e30f;
        if (k < deg) {
            u = srcs[s + k];
            float4 au = att4[u];
            e0 = au.x + er0; e0 = e0 > 0.f ? e0 : 0.2f * e0;
            e1 = au.y + er1; e1 = e1 > 0.f ? e1 : 0.2f * e1;
        }
        float mc0 = e0, mc1 = e1;
        #pragma unroll
        for (int mm = 1; mm < 64; mm <<= 1) {
            mc0 = fmaxf(mc0, __shfl_xor(mc0, mm));
            mc1 = fmaxf(mc1, __shfl_xor(mc1, mm));
        }
        float m0n = fmaxf(m0, mc0), m1n = fmaxf(m1, mc1);
        float f0 = __expf(m0 - m0n), f1 = __expf(m1 - m1n);
        float w0 = (k < deg) ? __expf(e0 - m0n) : 0.f;
        float w1 = (k < deg) ? __expf(e1 - m1n) : 0.f;
        float s0 = w0, s1 = w1;
        #pragma unroll
        for (int mm = 1; mm < 64; mm <<= 1) {
            s0 += __shfl_xor(s0, mm);
            s1 += __shfl_xor(s1, mm);
        }
        d0 = d0 * f0 + s0;
        d1 = d1 * f1 + s1;
        float fa = headbit ? f1 : f0;
        a0 *= fa; a1 *= fa; a2 *= fa; a3 *= fa;
        a4 *= fa; a5 *= fa; a6 *= fa; a7 *= fa;
        m0 = m0n; m1 = m1n;

        int k2 = 0;
        // 4 pairs (8 edges) per iter: 4 independent 1 KB wave-loads in flight
        for (; k2 + 8 <= cn; k2 += 8) {
            int idxA = k2 + halfsel, idxB = k2 + 2 + halfsel;
            int idxC = k2 + 4 + halfsel, idxD = k2 + 6 + halfsel;
            int uA = __shfl(u, idxA), uB = __shfl(u, idxB);
            int uC = __shfl(u, idxC), uD = __shfl(u, idxD);
            float wA0 = __shfl(w0, idxA), wA1 = __shfl(w1, idxA);
            float wB0 = __shfl(w0, idxB), wB1 = __shfl(w1, idxB);
            float wC0 = __shfl(w0, idxC), wC1 = __shfl(w1, idxC);
            float wD0 = __shfl(w0, idxD), wD1 = __shfl(w1, idxD);
            float wA = headbit ? wA1 : wA0;
            float wB = headbit ? wB1 : wB0;
            float wC = headbit ? wC1 : wC0;
            float wD = headbit ? wD1 : wD0;
            uint4 gA = feat4[(size_t)uA * 32 + seg];
            uint4 gB = feat4[(size_t)uB * 32 + seg];
            uint4 gC = feat4[(size_t)uC * 32 + seg];
            uint4 gD = feat4[(size_t)uD * 32 + seg];
            a0 += wA * bflo(gA.x) + wB * bflo(gB.x) + wC * bflo(gC.x) + wD * bflo(gD.x);
            a1 += wA * bfhi(gA.x) + wB * bfhi(gB.x) + wC * bfhi(gC.x) + wD * bfhi(gD.x);
            a2 += wA * bflo(gA.y) + wB * bflo(gB.y) + wC * bflo(gC.y) + wD * bflo(gD.y);
            a3 += wA * bfhi(gA.y) + wB * bfhi(gB.y) + wC * bfhi(gC.y) + wD * bfhi(gD.y);
            a4 += wA * bflo(gA.z) + wB * bflo(gB.z) + wC * bflo(gC.z) + wD * bflo(gD.z);
            a5 += wA * bfhi(gA.z) + wB * bfhi(gB.z) + wC * bfhi(gC.z) + wD * bfhi(gD.z);
            a6 += wA * bflo(gA.w) + wB * bflo(gB.w) + wC * bflo(gC.w) + wD * bflo(gD.w);
            a7 += wA * bfhi(gA.w) + wB * bfhi(gB.w) + wC * bfhi(gC.w) + wD * bfhi(gD.w);
        }
        for (; k2 < cn; k2 += 2) {
            int idx = k2 + halfsel;
            bool ok = idx < cn;
            int idxc = ok ? idx : 0;
            int uu = __shfl(u, idxc);
            float wk0 = __shfl(w0, idxc), wk1 = __shfl(w1, idxc);
            float wk = headbit ? wk1 : wk0;
            if (!ok) wk = 0.f;
            uint4 g = feat4[(size_t)uu * 32 + seg];
            a0 += wk * bflo(g.x); a1 += wk * bfhi(g.x);
            a2 += wk * bflo(g.y); a3 += wk * bfhi(g.y);
            a4 += wk * bflo(g.z); a5 += wk * bfhi(g.z);
            a6 += wk * bflo(g.w); a7 += wk * bfhi(g.w);
        }
    }
    // merge edge-parity halves (lane ^ 32)
    a0 += __shfl_xor(a0, 32); a1 += __shfl_xor(a1, 32);
    a2 += __shfl_xor(a2, 32); a3 += __shfl_xor(a3, 32);
    a4 += __shfl_xor(a4, 32); a5 += __shfl_xor(a5, 32);
    a6 += __shfl_xor(a6, 32); a7 += __shfl_xor(a7, 32);
    float dh = headbit ? d1 : d0;
    float r = 1.f / (dh + 1e-9f);
    float o0 = fmaxf(a0 * r, 0.f), o1 = fmaxf(a1 * r, 0.f);
    float o2 = fmaxf(a2 * r, 0.f), o3 = fmaxf(a3 * r, 0.f);
    float o4 = fmaxf(a4 * r, 0.f), o5 = fmaxf(a5 * r, 0.f);
    float o6 = fmaxf(a6 * r, 0.f), o7 = fmaxf(a7 * r, 0.f);
    // head-mean with partner lane ^16 (other head, same columns)
    o0 = 0.5f * (o0 + __shfl_xor(o0, 16)); o1 = 0.5f * (o1 + __shfl_xor(o1, 16));
    o2 = 0.5f * (o2 + __shfl_xor(o2, 16)); o3 = 0.5f * (o3 + __shfl_xor(o3, 16));
    o4 = 0.5f * (o4 + __shfl_xor(o4, 16)); o5 = 0.5f * (o5 + __shfl_xor(o5, 16));
    o6 = 0.5f * (o6 + __shfl_xor(o6, 16)); o7 = 0.5f * (o7 + __shfl_xor(o7, 16));
    if (lane < 16) {
        uint4 q;
        q.x = packbf(o0, o1); q.y = packbf(o2, o3);
        q.z = packbf(o4, o5); q.w = packbf(o6, o7);
        hout4[(size_t)v * 16 + lane] = q;
    }
}

// ---------------- fused pair MLP via MFMA ----------------
__global__ __launch_bounds__(256) void mlp_mfma(const u16* __restrict__ hf,
                                                const int* __restrict__ x1,
                                                const int* __restrict__ x2,
                                                const u16* __restrict__ w1p,
                                                const float* __restrict__ b1,
                                                const float* __restrict__ w2,
                                                const float* __restrict__ b2,
                                                float* __restrict__ out) {
    __shared__ u16 z[64][392];
    int pbase = blockIdx.x * 64;
    int tid = threadIdx.x;
    const uint4* hfu4 = (const uint4*)hf;
    for (int id = tid; id < 64 * 16; id += 256) {
        int p = id >> 4, seg = id & 15;
        int gp = pbase + p;
        uint4 v1 = make_uint4(0u, 0u, 0u, 0u), v2 = v1;
        if (gp < NPAIR) {
            v1 = hfu4[x1[gp] * 16 + seg];
            v2 = hfu4[x2[gp] * 16 + seg];
        }
        int c8 = seg << 3;
        *(uint4*)&z[p][c8] = v1;
        *(uint4*)&z[p][128 + c8] = v2;
        uint4 vd;
        vd.x = packbf(fabsf(bflo(v1.x) - bflo(v2.x)), fabsf(bfhi(v1.x) - bfhi(v2.x)));
        vd.y = packbf(fabsf(bflo(v1.y) - bflo(v2.y)), fabsf(bfhi(v1.y) - bfhi(v2.y)));
        vd.z = packbf(fabsf(bflo(v1.z) - bflo(v2.z)), fabsf(bfhi(v1.z) - bfhi(v2.z)));
        vd.w = packbf(fabsf(bflo(v1.w) - bflo(v2.w)), fabsf(bfhi(v1.w) - bfhi(v2.w)));
        *(uint4*)&z[p][256 + c8] = vd;
    }
    __syncthreads();
    int l = tid & 63, w = tid >> 6;
    int lg = l >> 4, ln = l & 15;
    f32x4 acc[8];
    #pragma unroll
    for (int ct = 0; ct < 8; ++ct) acc[ct] = (f32x4){0.f, 0.f, 0.f, 0.f};
    const short8* wp = (const short8*)w1p;
    const u16* zr = &z[w * 16 + ln][lg * 8];
    for (int kt = 0; kt < 12; ++kt) {
        short8 a = *(const short8*)&zr[kt * 32];
        #pragma unroll
        for (int ct = 0; ct < 8; ++ct) {
            short8 b = wp[(kt * 8 + ct) * 64 + l];
            acc[ct] = __builtin_amdgcn_mfma_f32_16x16x32_bf16(a, b, acc[ct], 0, 0, 0);
        }
    }
    float b1v[8], w20[8], w21[8];
    #pragma unroll
    for (int ct = 0; ct < 8; ++ct) {
        int n = ct * 16 + ln;
        b1v[ct] = b1[n];
        w20[ct] = w2[n * 2 + 0];
        w21[ct] = w2[n * 2 + 1];
    }
    float ob0 = b2[0], ob1 = b2[1];
    #pragma unroll
    for (int r = 0; r < 4; ++r) {
        float p0 = 0.f, p1 = 0.f;
        #pragma unroll
        for (int ct = 0; ct < 8; ++ct) {
            float zv = fmaxf(acc[ct][r] + b1v[ct], 0.f);
            p0 += zv * w20[ct]; p1 += zv * w21[ct];
        }
        #pragma unroll
        for (int m = 1; m < 16; m <<= 1) { p0 += __shfl_xor(p0, m); p1 += __shfl_xor(p1, m); }
        int gp = pbase + w * 16 + lg * 4 + r;
        if (ln == 0 && gp < NPAIR) {
            out[gp * 2 + 0] = p0 + ob0;
            out[gp * 2 + 1] = p1 + ob1;
        }
    }
}

extern "C" void kernel_launch(void* const* d_in, const int* in_sizes, int n_in,
                              void* d_out, int out_size, void* d_ws, size_t ws_size,
                              hipStream_t stream) {
    const int*   src = (const int*)d_in[0];
    const int*   dst = (const int*)d_in[1];
    const float* h   = (const float*)d_in[2];
    const int*   x1  = (const int*)d_in[3];
    const int*   x2  = (const int*)d_in[4];
    const float* W0  = (const float*)d_in[5];
    const float* al0 = (const float*)d_in[6];
    const float* ar0 = (const float*)d_in[7];
    const float* W1  = (const float*)d_in[8];
    const float* al1 = (const float*)d_in[9];
    const float* ar1 = (const float*)d_in[10];
    const float* w1  = (const float*)d_in[11];
    const float* b1  = (const float*)d_in[12];
    const float* w2  = (const float*)d_in[13];
    const float* b2  = (const float*)d_in[14];
    float* out = (float*)d_out;

    char* ws = (char*)d_ws;
    size_t o = 0;
    auto alloc = [&](size_t bytes) { size_t r = o; o = (o + bytes + 255) & ~255UL; return r; };
    int* off    = (int*)(ws + alloc((NN + 1) * sizeof(int)));
    int* cursor = (int*)(ws + alloc(NN * sizeof(int)));
    int* bsums  = (int*)(ws + alloc(256 * sizeof(int)));
    int* srcs   = (int*)(ws + alloc(NE * sizeof(int)));
    float* att  = (float*)(ws + alloc((size_t)NN * 4 * sizeof(float)));
    u16* feat   = (u16*)(ws + alloc((size_t)NN * 256 * sizeof(u16)));
    u16* hb0    = (u16*)(ws + alloc((size_t)NN * 128 * sizeof(u16)));
    u16* hb1    = (u16*)(ws + alloc((size_t)NN * 128 * sizeof(u16)));
    u16* w1p    = (u16*)(ws + alloc((size_t)384 * 128 * sizeof(u16)));
    u16* w0pg   = (u16*)(ws + alloc((size_t)128 * 256 * sizeof(u16)));
    u16* w1pg   = (u16*)(ws + alloc((size_t)128 * 256 * sizeof(u16)));

    hipMemsetAsync(off, 0, (NN + 1) * sizeof(int), stream);
    hipMemsetAsync(cursor, 0, NN * sizeof(int), stream);

    int eblocks = (NE + 255) / 256;
    int nscan = NN + 1;
    int nb = (nscan + 255) / 256;
    count_kernel<<<eblocks, 256, 0, stream>>>(dst, off);
    scan1<<<nb, 256, 0, stream>>>(off, bsums, nscan);
    scan2<<<1, 256, 0, stream>>>(bsums, nb);
    scan3<<<nb, 256, 0, stream>>>(off, bsums, nscan);
    fill_kernel<<<eblocks, 256, 0, stream>>>(src, dst, off, cursor, srcs);
    pack_all<<<448, 256, 0, stream>>>(W0, W1, w1, w0pg, w1pg, w1p);

    int gblocks = (NN + 63) / 64;
    // layer 0 (A fp32)
    gemm_mfma<false><<<gblocks, 256, 0, stream>>>((const void*)h, w0pg, al0, ar0, feat, att, NN);
    aggregate<<<(NN + 3) / 4, 256, 0, stream>>>(feat, off, srcs, att, hb0);
    // layer 1 (A bf16)
    gemm_mfma<true><<<gblocks, 256, 0, stream>>>((const void*)hb0, w1pg, al1, ar1, feat, att, NN);
    aggregate<<<(NN + 3) / 4, 256, 0, stream>>>(feat, off, srcs, att, hb1);
    // pair MLP (MFMA)
    mlp_mfma<<<(NPAIR + 63) / 64, 256, 0, stream>>>(hb1, x1, x2, w1p, b1, w2, b2, out);
}